// Round 7
// baseline (269.161 us; speedup 1.0000x reference)
//
#include <hip/hip_runtime.h>
#include <math.h>

#define BB 2
#define CC 512
#define NN 2304
#define NH 8
#define DD 512
#define D3 1536
#define WIDTH 48
#define C1 0.18033688f  // 0.125 * log2(e)
#define NSPLIT 4
#define KTILES 9        // 36 k-tiles / NSPLIT

typedef _Float16 h8 __attribute__((ext_vector_type(8)));
typedef _Float16 h4 __attribute__((ext_vector_type(4)));
typedef _Float16 h2 __attribute__((ext_vector_type(2)));
typedef float f4 __attribute__((ext_vector_type(4)));

__device__ __forceinline__ void gload16(const void* g, void* s) {
  __builtin_amdgcn_global_load_lds(
      (const __attribute__((address_space(1))) unsigned int*)g,
      (__attribute__((address_space(3))) unsigned int*)s, 16, 0, 0);
}

// ---------------------------------------------------------------------------
// Kernel 0: fused prep. blockIdx.y selects job:
//  y=0: Fresnel bias table in MFMA C-frag order, pre-scaled by log2e (648 blk)
//  y=1: transpose-convert x[b][c][n] fp32 -> xt[b][n][c] f16       (2304 blk)
//  y=2: convert w_qkv/w_out fp32 -> f16                            (1024 blk)
// ---------------------------------------------------------------------------
__global__ __launch_bounds__(256) void prep_k(
    const float* __restrict__ x, const float* __restrict__ wq,
    const float* __restrict__ wo, const float* __restrict__ wavp,
    _Float16* __restrict__ btf, _Float16* __restrict__ xt,
    _Float16* __restrict__ wqh, _Float16* __restrict__ woh)
{
  __shared__ float Ls[32][33];
  const int t = threadIdx.x;
  const int bx = blockIdx.x;
  const int job = blockIdx.y;

  if (job == 0) {
    if (bx >= 648) return;
    const int gid = bx * 256 + t;
    const int tile = gid >> 7, tid = gid & 127;
    const int qbk = tile / 36, ktk = tile % 36;
    const int w = tid >> 6, quad = (tid >> 4) & 3, l15 = tid & 15;
    const float pc = 6.283185307179586f / (fabsf(wavp[0]) * (float)WIDTH + 1e-6f);
    _Float16* o = btf + (((size_t)qbk * 36 + ktk) * 128 + tid) * 32;
#pragma unroll
    for (int g = 0; g < 4; ++g) {
      h8 v;
#pragma unroll
      for (int e = 0; e < 8; ++e) {
        const int j = g * 8 + e;
        const int nt = j >> 4, mt = (j >> 2) & 3, r = j & 3;
        const int q = qbk * 64 + w * 32 + nt * 16 + l15;
        const int k = ktk * 64 + mt * 16 + quad * 4 + r;
        const float dy = (float)(q / WIDTH) - (float)(k / WIDTH);
        const float dx = (float)(q % WIDTH) - (float)(k % WIDTH);
        const float dist = sqrtf(dy * dy + dx * dx + 1e-8f);
        v[e] = (_Float16)(0.1f * __cosf(dist * pc) * 1.44269504f);
      }
      *(h8*)(o + g * 8) = v;
    }
  } else if (job == 1) {
    const int b = bx / 1152, rem = bx % 1152;
    const int c0 = (rem / 72) * 32, n0 = (rem % 72) * 32;
#pragma unroll
    for (int p = 0; p < 4; ++p) {
      const int cl = (t >> 5) + p * 8, nl = t & 31;
      Ls[cl][nl] = x[((size_t)b * CC + c0 + cl) * NN + n0 + nl];
    }
    __syncthreads();
#pragma unroll
    for (int p = 0; p < 2; ++p) {
      const int nl = (t >> 4) + p * 16, cl = (t & 15) * 2;
      h2 v = {(_Float16)Ls[cl][nl], (_Float16)Ls[cl + 1][nl]};
      *(h2*)(xt + ((size_t)b * NN + n0 + nl) * CC + c0 + cl) = v;
    }
  } else {
    if (bx >= 1024) return;
    const int idx = bx * 256 + t;
    const int NQ = (D3 * CC) / 4;
    if (idx < NQ) {
      float4 v = *(const float4*)(wq + (size_t)idx * 4);
      h4 o = {(_Float16)v.x, (_Float16)v.y, (_Float16)v.z, (_Float16)v.w};
      *(h4*)(wqh + (size_t)idx * 4) = o;
    } else {
      const int j = idx - NQ;
      float4 v = *(const float4*)(wo + (size_t)j * 4);
      h4 o = {(_Float16)v.x, (_Float16)v.y, (_Float16)v.z, (_Float16)v.w};
      *(h4*)(woh + (size_t)j * 4) = o;
    }
  }
}

// ---------------------------------------------------------------------------
// Kernel 1: qkv MFMA GEMM. 64x64 tile, one wave/block, double-buffered
// global_load_lds staging. q/k -> [b][h][n][dh]; v -> [b][h][dh][n] (swapped
// MFMA args).
// ---------------------------------------------------------------------------
__global__ __launch_bounds__(64) void qkv_gemm_k(
    const _Float16* __restrict__ xt, const _Float16* __restrict__ wqh,
    _Float16* __restrict__ qb, _Float16* __restrict__ kb,
    _Float16* __restrict__ vb)
{
  __shared__ _Float16 Xs[2][64][32];
  __shared__ _Float16 Ws[2][64][32];
  const int t = threadIdx.x;
  const int l15 = t & 15, quad = t >> 4;
  const int n0 = blockIdx.x * 64;
  const int d0 = blockIdx.y * 64;
  const int b  = blockIdx.z;
  const bool isv = (d0 >= 2 * DD);
  const _Float16* xb = xt + (size_t)b * NN * CC;
  const int srow = t >> 2, scol = (t & 3) * 8;

  f4 acc[4][4];
#pragma unroll
  for (int mt = 0; mt < 4; ++mt)
#pragma unroll
    for (int nt = 0; nt < 4; ++nt) acc[mt][nt] = (f4)(0.f);

  auto stage = [&](int bf, int c0) {
#pragma unroll
    for (int ci = 0; ci < 4; ++ci) {
      const int row = ci * 16 + srow;
      gload16(xb + (size_t)(n0 + row) * CC + c0 + scol,
              &Xs[bf][0][0] + ci * 512);
      gload16(wqh + (size_t)(d0 + row) * CC + c0 + scol,
              &Ws[bf][0][0] + ci * 512);
    }
  };

  stage(0, 0);
  for (int i = 0; i < 16; ++i) {
    const int cur = i & 1;
    __syncthreads();
    if (i < 15) stage(cur ^ 1, (i + 1) * 32);
    h8 wfr[4], xfr[4];
#pragma unroll
    for (int mt = 0; mt < 4; ++mt)
      wfr[mt] = *(const h8*)&Ws[cur][mt * 16 + l15][quad * 8];
#pragma unroll
    for (int nt = 0; nt < 4; ++nt)
      xfr[nt] = *(const h8*)&Xs[cur][nt * 16 + l15][quad * 8];
    if (!isv) {
#pragma unroll
      for (int mt = 0; mt < 4; ++mt)
#pragma unroll
        for (int nt = 0; nt < 4; ++nt)
          acc[mt][nt] = __builtin_amdgcn_mfma_f32_16x16x32_f16(
              wfr[mt], xfr[nt], acc[mt][nt], 0, 0, 0);
    } else {
#pragma unroll
      for (int mt = 0; mt < 4; ++mt)
#pragma unroll
        for (int nt = 0; nt < 4; ++nt)
          acc[mt][nt] = __builtin_amdgcn_mfma_f32_16x16x32_f16(
              xfr[nt], wfr[mt], acc[mt][nt], 0, 0, 0);
    }
  }

  if (!isv) {
    const int which = d0 >> 9;
    _Float16* buf = which == 0 ? qb : kb;
    const int h = (d0 & 511) >> 6;
#pragma unroll
    for (int mt = 0; mt < 4; ++mt) {
      const int dh = mt * 16 + quad * 4;
#pragma unroll
      for (int nt = 0; nt < 4; ++nt) {
        const int token = n0 + nt * 16 + l15;
        h4 o = {(_Float16)acc[mt][nt][0], (_Float16)acc[mt][nt][1],
                (_Float16)acc[mt][nt][2], (_Float16)acc[mt][nt][3]};
        *(h4*)(buf + (((size_t)b * NH + h) * NN + token) * 64 + dh) = o;
      }
    }
  } else {
    const int h = (d0 - 2 * DD) >> 6;
#pragma unroll
    for (int mt = 0; mt < 4; ++mt) {
      const int dh = mt * 16 + l15;
#pragma unroll
      for (int nt = 0; nt < 4; ++nt) {
        const int token = n0 + nt * 16 + quad * 4;
        h4 o = {(_Float16)acc[mt][nt][0], (_Float16)acc[mt][nt][1],
                (_Float16)acc[mt][nt][2], (_Float16)acc[mt][nt][3]};
        *(h4*)(vb + (((size_t)b * NH + h) * 64 + dh) * NN + token) = o;
      }
    }
  }
}

// ---------------------------------------------------------------------------
// Kernel 2: MFMA flash attention, K-split x4 (R4 loop structure). No-max
// softmax (p = exp2(s*C1 + bias')) -> splits combine by plain addition:
// epilogue atomically accumulates UNNORMALIZED O (f32) and l into global.
// ---------------------------------------------------------------------------
__global__ __launch_bounds__(128, 3) void attn_k(
    const _Float16* __restrict__ qb, const _Float16* __restrict__ kb,
    const _Float16* __restrict__ vb, const _Float16* __restrict__ btf,
    float* __restrict__ Oacc, float* __restrict__ lsum)
{
  __shared__ _Float16 Ks[64][72];
  __shared__ _Float16 Vs[64][72];
  __shared__ _Float16 Ps[2][32][72];

  const int t    = threadIdx.x;
  const int lane = t & 63;
  const int w    = t >> 6;
  const int l15  = lane & 15;
  const int quad = lane >> 4;
  const int qt = blockIdx.x >> 2;   // 64-query tile 0..35
  const int s  = blockIdx.x & 3;    // k-split quarter
  const int h = blockIdx.y, b = blockIdx.z;
  const int n0 = qt * 64;
  const size_t base = ((size_t)b * NH + h) * NN * 64;
  const _Float16* qp = qb + base;
  const _Float16* kp = kb + base;
  const _Float16* vp = vb + base;  // [dh][n]

  h8 qf[2][2];
#pragma unroll
  for (int nt = 0; nt < 2; ++nt)
#pragma unroll
    for (int ks = 0; ks < 2; ++ks)
      qf[nt][ks] = *(const h8*)(qp + (size_t)(n0 + w * 32 + nt * 16 + l15) * 64 +
                                ks * 32 + quad * 8);

  f4 oc[4][2];
#pragma unroll
  for (int mt = 0; mt < 4; ++mt)
#pragma unroll
    for (int nt = 0; nt < 2; ++nt) oc[mt][nt] = (f4)(0.f);
  float lacc[2][4] = {};

  const int srow = t >> 3, soff = (t & 7) * 8;
  const _Float16* bp = btf + (((size_t)qt * 36 + s * KTILES) * 128 + t) * 32;

  for (int kt = 0; kt < KTILES; ++kt) {
    const int k0 = (s * KTILES + kt) * 64;
    h8 kr[4], vr[4], br[4];
#pragma unroll
    for (int r = 0; r < 4; ++r) {
      const int row = srow + r * 16;
      kr[r] = *(const h8*)(kp + (size_t)(k0 + row) * 64 + soff);
      vr[r] = *(const h8*)(vp + (size_t)row * NN + k0 + soff);
      br[r] = *(const h8*)(bp + r * 8);
    }
    bp += 128 * 32;
    __syncthreads();  // all waves done reading previous tile's LDS
#pragma unroll
    for (int r = 0; r < 4; ++r) {
      const int row = srow + r * 16;
      *(h8*)&Ks[row][soff] = kr[r];
      *(h8*)&Vs[row][soff] = vr[r];
    }
    __syncthreads();

    // ---- S^T = K * Q^T ----
    f4 st[4][2];
#pragma unroll
    for (int mt = 0; mt < 4; ++mt)
#pragma unroll
      for (int nt = 0; nt < 2; ++nt) st[mt][nt] = (f4)(0.f);
#pragma unroll
    for (int ks = 0; ks < 2; ++ks)
#pragma unroll
      for (int mt = 0; mt < 4; ++mt) {
        h8 kf = *(const h8*)&Ks[mt * 16 + l15][ks * 32 + quad * 8];
#pragma unroll
        for (int nt = 0; nt < 2; ++nt)
          st[mt][nt] = __builtin_amdgcn_mfma_f32_16x16x32_f16(
              kf, qf[nt][ks], st[mt][nt], 0, 0, 0);
      }

    // ---- p = exp2(s*C1 + bias'), no max tracking ----
#pragma unroll
    for (int nt = 0; nt < 2; ++nt) {
      const int q = nt * 16 + l15;
#pragma unroll
      for (int mt = 0; mt < 4; ++mt) {
        h4 pk;
#pragma unroll
        for (int r = 0; r < 4; ++r) {
          const int j = nt * 16 + mt * 4 + r;
          const float bias = (float)br[j >> 3][j & 7];
          const float p = __builtin_exp2f(st[mt][nt][r] * C1 + bias);
          lacc[nt][r] += p;
          pk[r] = (_Float16)p;
        }
        *(h4*)&Ps[w][q][mt * 16 + quad * 4] = pk;  // wave-private
      }
    }

    // ---- O^T += V^T * P^T ----
#pragma unroll
    for (int ks = 0; ks < 2; ++ks) {
      h8 pf[2];
#pragma unroll
      for (int nt = 0; nt < 2; ++nt)
        pf[nt] = *(const h8*)&Ps[w][nt * 16 + l15][ks * 32 + quad * 8];
#pragma unroll
      for (int mt = 0; mt < 4; ++mt) {
        h8 vf = *(const h8*)&Vs[mt * 16 + l15][ks * 32 + quad * 8];
#pragma unroll
        for (int nt = 0; nt < 2; ++nt)
          oc[mt][nt] = __builtin_amdgcn_mfma_f32_16x16x32_f16(
              vf, pf[nt], oc[mt][nt], 0, 0, 0);
      }
    }
  }

  // ---- epilogue: atomic accumulate unnormalized O and l ----
#pragma unroll
  for (int nt = 0; nt < 2; ++nt) {
    float l = lacc[nt][0] + lacc[nt][1] + lacc[nt][2] + lacc[nt][3];
    l += __shfl_xor(l, 16);
    l += __shfl_xor(l, 32);
    const int qi = n0 + w * 32 + nt * 16 + l15;
    float* od = Oacc + ((size_t)b * NN + qi) * DD + h * 64;
#pragma unroll
    for (int mt = 0; mt < 4; ++mt)
#pragma unroll
      for (int r = 0; r < 4; ++r)
        atomicAdd(od + mt * 16 + quad * 4 + r, oc[mt][nt][r]);
    if (quad == 0)
      atomicAdd(lsum + ((size_t)b * NH + h) * NN + qi, l);
  }
}

// ---------------------------------------------------------------------------
// Kernel 3: fused normalize + out-projection GEMM. 64x64 tile, one wave.
// Stages A = Oacc[n][d] / lsum[b,h(d),n] as f16 into LDS (reg-prefetched),
// B = woh via double-buffered gload16. out[b][o][n] += bias.
// ---------------------------------------------------------------------------
__global__ __launch_bounds__(64) void outcomb_k(
    const float* __restrict__ Oacc, const float* __restrict__ lsum,
    const _Float16* __restrict__ woh, const float* __restrict__ bias,
    float* __restrict__ out)
{
  __shared__ _Float16 Hs[64][32];
  __shared__ _Float16 Ws2[2][64][32];
  const int t = threadIdx.x;
  const int l15 = t & 15, quad = t >> 4;
  const int n0 = blockIdx.x * 64;
  const int o0 = blockIdx.y * 64;
  const int b  = blockIdx.z;
  const int srow = t >> 2, scol = (t & 3) * 8;

  f4 acc[4][4];
#pragma unroll
  for (int mt = 0; mt < 4; ++mt)
#pragma unroll
    for (int nt = 0; nt < 4; ++nt) acc[mt][nt] = (f4)(0.f);

  auto stage_w = [&](int bf, int c0) {
#pragma unroll
    for (int ci = 0; ci < 4; ++ci)
      gload16(woh + (size_t)(o0 + ci * 16 + srow) * DD + c0 + scol,
              &Ws2[bf][0][0] + ci * 512);
  };

  float4 orow[4][2];
  float invr[4];
  auto load_o = [&](int c0) {
    const int h = c0 >> 6;
#pragma unroll
    for (int ci = 0; ci < 4; ++ci) {
      const int row = n0 + ci * 16 + srow;
      const float* p = Oacc + ((size_t)b * NN + row) * DD + c0 + scol;
      orow[ci][0] = *(const float4*)p;
      orow[ci][1] = *(const float4*)(p + 4);
      invr[ci] = 1.f / lsum[((size_t)b * NH + h) * NN + row];
    }
  };

  stage_w(0, 0);
  load_o(0);
  for (int i = 0; i < 16; ++i) {
    const int cur = i & 1;
    __syncthreads();  // drains: prior LDS reads, stage_w(cur) vmcnt
    // combine current O regs -> Hs
#pragma unroll
    for (int ci = 0; ci < 4; ++ci) {
      const float iv = invr[ci];
      h8 v = {(_Float16)(orow[ci][0].x * iv), (_Float16)(orow[ci][0].y * iv),
              (_Float16)(orow[ci][0].z * iv), (_Float16)(orow[ci][0].w * iv),
              (_Float16)(orow[ci][1].x * iv), (_Float16)(orow[ci][1].y * iv),
              (_Float16)(orow[ci][1].z * iv), (_Float16)(orow[ci][1].w * iv)};
      *(h8*)&Hs[ci * 16 + srow][scol] = v;
    }
    if (i < 15) {
      stage_w(cur ^ 1, (i + 1) * 32);
      load_o((i + 1) * 32);
    }
    h8 hf[4], wf[4];
#pragma unroll
    for (int mt = 0; mt < 4; ++mt)
      hf[mt] = *(const h8*)&Hs[mt * 16 + l15][quad * 8];
#pragma unroll
    for (int nt = 0; nt < 4; ++nt)
      wf[nt] = *(const h8*)&Ws2[cur][nt * 16 + l15][quad * 8];
#pragma unroll
    for (int mt = 0; mt < 4; ++mt)
#pragma unroll
      for (int nt = 0; nt < 4; ++nt)
        acc[mt][nt] = __builtin_amdgcn_mfma_f32_16x16x32_f16(
            hf[mt], wf[nt], acc[mt][nt], 0, 0, 0);
  }

#pragma unroll
  for (int nt = 0; nt < 4; ++nt) {
    const int o = o0 + nt * 16 + l15;
    const float bv = bias[o];
#pragma unroll
    for (int mt = 0; mt < 4; ++mt) {
      const int token = n0 + mt * 16 + quad * 4;
      float4 v = {acc[mt][nt][0] + bv, acc[mt][nt][1] + bv,
                  acc[mt][nt][2] + bv, acc[mt][nt][3] + bv};
      *(float4*)(out + ((size_t)b * DD + o) * NN + token) = v;
    }
  }
}

extern "C" void kernel_launch(void* const* d_in, const int* in_sizes, int n_in,
                              void* d_out, int out_size, void* d_ws, size_t ws_size,
                              hipStream_t stream)
{
  (void)in_sizes; (void)n_in; (void)out_size; (void)ws_size;
  const float* x     = (const float*)d_in[0];
  const float* w_qkv = (const float*)d_in[1];
  const float* w_out = (const float*)d_in[2];
  const float* b_out = (const float*)d_in[3];
  const float* wav   = (const float*)d_in[4];
  float* out = (float*)d_out;

  const size_t SZ  = (size_t)BB * NH * NN * 64;   // 2,359,296 (h16)
  const size_t BTF = (size_t)36 * 36 * 128 * 32;  // 5,308,416 (h16)

  _Float16* qb  = (_Float16*)d_ws;
  _Float16* kb  = qb + SZ;
  _Float16* vb  = kb + SZ;
  _Float16* btf = vb + SZ;
  float* Oacc   = (float*)(btf + BTF);          // B*NN*DD f32 (unnormalized O)
  float* lsm    = Oacc + (size_t)BB * NN * DD;  // B*NH*NN f32
  _Float16* woh = (_Float16*)(lsm + (size_t)BB * NH * NN);
  // aliases (lifetime-disjoint; memset runs AFTER qkv_gemm):
  _Float16* xt  = (_Float16*)Oacc;              // x^T f16, dead after qkv
  _Float16* wqh = xt + SZ;                      // w_qkv f16, dead after qkv
  // total ws: 3*SZ*2 + BTF*2 + (B*NN*DD + B*NH*NN)*4 + DD*DD*2 = ~34.9 MB

  prep_k    <<<dim3(2304, 3), 256, 0, stream>>>(x, w_qkv, w_out, wav,
                                                btf, xt, wqh, woh);
  qkv_gemm_k<<<dim3(NN / 64, D3 / 64, BB), 64, 0, stream>>>(xt, wqh, qb, kb, vb);
  hipMemsetAsync(Oacc, 0,
                 ((size_t)BB * NN * DD + (size_t)BB * NH * NN) * sizeof(float),
                 stream);
  attn_k    <<<dim3(NN / 64 * NSPLIT, NH, BB), 128, 0, stream>>>(
                 qb, kb, vb, btf, Oacc, lsm);
  outcomb_k <<<dim3(NN / 64, DD / 64, BB), 64, 0, stream>>>(
                 Oacc, lsm, woh, b_out, out);
}

// Round 8
// 170.152 us; speedup vs baseline: 1.5819x; 1.5819x over previous
//
#include <hip/hip_runtime.h>
#include <math.h>

#define BB 2
#define CC 512
#define NN 2304
#define NH 8
#define DD 512
#define D3 1536
#define WIDTH 48
#define C1 0.18033688f  // 0.125 * log2(e)
#define NSPLIT 2
#define KTILES 18       // 36 k-tiles / NSPLIT

typedef _Float16 h8 __attribute__((ext_vector_type(8)));
typedef _Float16 h4 __attribute__((ext_vector_type(4)));
typedef _Float16 h2 __attribute__((ext_vector_type(2)));
typedef float f4 __attribute__((ext_vector_type(4)));

__device__ __forceinline__ void gload16(const void* g, void* s) {
  __builtin_amdgcn_global_load_lds(
      (const __attribute__((address_space(1))) unsigned int*)g,
      (__attribute__((address_space(3))) unsigned int*)s, 16, 0, 0);
}

// ---------------------------------------------------------------------------
// Kernel 0: fused prep. blockIdx.y selects job:
//  y=0: Fresnel bias table in MFMA C-frag order, pre-scaled by log2e (648 blk)
//  y=1: transpose-convert x[b][c][n] fp32 -> xt[b][n][c] f16       (2304 blk)
//  y=2: convert w_qkv/w_out fp32 -> f16                            (1024 blk)
// ---------------------------------------------------------------------------
__global__ __launch_bounds__(256) void prep_k(
    const float* __restrict__ x, const float* __restrict__ wq,
    const float* __restrict__ wo, const float* __restrict__ wavp,
    _Float16* __restrict__ btf, _Float16* __restrict__ xt,
    _Float16* __restrict__ wqh, _Float16* __restrict__ woh)
{
  __shared__ float Ls[32][33];
  const int t = threadIdx.x;
  const int bx = blockIdx.x;
  const int job = blockIdx.y;

  if (job == 0) {
    if (bx >= 648) return;
    const int gid = bx * 256 + t;
    const int tile = gid >> 7, tid = gid & 127;
    const int qbk = tile / 36, ktk = tile % 36;
    const int w = tid >> 6, quad = (tid >> 4) & 3, l15 = tid & 15;
    const float pc = 6.283185307179586f / (fabsf(wavp[0]) * (float)WIDTH + 1e-6f);
    _Float16* o = btf + (((size_t)qbk * 36 + ktk) * 128 + tid) * 32;
#pragma unroll
    for (int g = 0; g < 4; ++g) {
      h8 v;
#pragma unroll
      for (int e = 0; e < 8; ++e) {
        const int j = g * 8 + e;
        const int nt = j >> 4, mt = (j >> 2) & 3, r = j & 3;
        const int q = qbk * 64 + w * 32 + nt * 16 + l15;
        const int k = ktk * 64 + mt * 16 + quad * 4 + r;
        const float dy = (float)(q / WIDTH) - (float)(k / WIDTH);
        const float dx = (float)(q % WIDTH) - (float)(k % WIDTH);
        const float dist = sqrtf(dy * dy + dx * dx + 1e-8f);
        v[e] = (_Float16)(0.1f * __cosf(dist * pc) * 1.44269504f);
      }
      *(h8*)(o + g * 8) = v;
    }
  } else if (job == 1) {
    const int b = bx / 1152, rem = bx % 1152;
    const int c0 = (rem / 72) * 32, n0 = (rem % 72) * 32;
#pragma unroll
    for (int p = 0; p < 4; ++p) {
      const int cl = (t >> 5) + p * 8, nl = t & 31;
      Ls[cl][nl] = x[((size_t)b * CC + c0 + cl) * NN + n0 + nl];
    }
    __syncthreads();
#pragma unroll
    for (int p = 0; p < 2; ++p) {
      const int nl = (t >> 4) + p * 16, cl = (t & 15) * 2;
      h2 v = {(_Float16)Ls[cl][nl], (_Float16)Ls[cl + 1][nl]};
      *(h2*)(xt + ((size_t)b * NN + n0 + nl) * CC + c0 + cl) = v;
    }
  } else {
    if (bx >= 1024) return;
    const int idx = bx * 256 + t;
    const int NQ = (D3 * CC) / 4;
    if (idx < NQ) {
      float4 v = *(const float4*)(wq + (size_t)idx * 4);
      h4 o = {(_Float16)v.x, (_Float16)v.y, (_Float16)v.z, (_Float16)v.w};
      *(h4*)(wqh + (size_t)idx * 4) = o;
    } else {
      const int j = idx - NQ;
      float4 v = *(const float4*)(wo + (size_t)j * 4);
      h4 o = {(_Float16)v.x, (_Float16)v.y, (_Float16)v.z, (_Float16)v.w};
      *(h4*)(woh + (size_t)j * 4) = o;
    }
  }
}

// ---------------------------------------------------------------------------
// Kernel 1: qkv MFMA GEMM. 128(n) x 64(d) tile, 2 waves (each 64x64),
// double-buffered gload16 staging; W tile shared by both waves.
// q/k -> [b][h][n][dh]; v blocks use swapped MFMA args -> [b][h][dh][n].
// ---------------------------------------------------------------------------
__global__ __launch_bounds__(128) void qkv_gemm_k(
    const _Float16* __restrict__ xt, const _Float16* __restrict__ wqh,
    _Float16* __restrict__ qb, _Float16* __restrict__ kb,
    _Float16* __restrict__ vb)
{
  __shared__ _Float16 Xs[2][128][32];
  __shared__ _Float16 Ws[2][64][32];
  const int t = threadIdx.x;
  const int lane = t & 63, w = t >> 6;
  const int l15 = lane & 15, quad = lane >> 4;
  const int n0 = blockIdx.x * 128;
  const int d0 = blockIdx.y * 64;
  const int b  = blockIdx.z;
  const bool isv = (d0 >= 2 * DD);
  const _Float16* xb = xt + (size_t)b * NN * CC;
  const int lrow = lane >> 2, lcol = (lane & 3) * 8;  // 4 lanes per 32-col row

  f4 acc[4][4];
#pragma unroll
  for (int mt = 0; mt < 4; ++mt)
#pragma unroll
    for (int nt = 0; nt < 4; ++nt) acc[mt][nt] = (f4)(0.f);

  // wave w stages Xs rows [w*64, w*64+64) and Ws rows [w*32, w*32+32)
  auto stage = [&](int bf, int c0) {
#pragma unroll
    for (int k = 0; k < 4; ++k) {
      const int row = w * 64 + k * 16 + lrow;
      gload16(xb + (size_t)(n0 + row) * CC + c0 + lcol,
              &Xs[bf][w * 64 + k * 16][0]);
    }
#pragma unroll
    for (int k = 0; k < 2; ++k) {
      const int row = w * 32 + k * 16 + lrow;
      gload16(wqh + (size_t)(d0 + row) * CC + c0 + lcol,
              &Ws[bf][w * 32 + k * 16][0]);
    }
  };

  stage(0, 0);
  for (int i = 0; i < 16; ++i) {
    const int cur = i & 1;
    __syncthreads();  // drains vmcnt -> stage(cur) complete
    if (i < 15) stage(cur ^ 1, (i + 1) * 32);
    h8 wfr[4], xfr[4];
#pragma unroll
    for (int mt = 0; mt < 4; ++mt)
      wfr[mt] = *(const h8*)&Ws[cur][mt * 16 + l15][quad * 8];
#pragma unroll
    for (int nt = 0; nt < 4; ++nt)
      xfr[nt] = *(const h8*)&Xs[cur][w * 64 + nt * 16 + l15][quad * 8];
    if (!isv) {
#pragma unroll
      for (int mt = 0; mt < 4; ++mt)
#pragma unroll
        for (int nt = 0; nt < 4; ++nt)
          acc[mt][nt] = __builtin_amdgcn_mfma_f32_16x16x32_f16(
              wfr[mt], xfr[nt], acc[mt][nt], 0, 0, 0);
    } else {
#pragma unroll
      for (int mt = 0; mt < 4; ++mt)
#pragma unroll
        for (int nt = 0; nt < 4; ++nt)
          acc[mt][nt] = __builtin_amdgcn_mfma_f32_16x16x32_f16(
              xfr[nt], wfr[mt], acc[mt][nt], 0, 0, 0);
    }
  }

  if (!isv) {
    const int which = d0 >> 9;  // 0 = q, 1 = k
    _Float16* buf = which == 0 ? qb : kb;
    const int h = (d0 & 511) >> 6;
#pragma unroll
    for (int mt = 0; mt < 4; ++mt) {
      const int dh = mt * 16 + quad * 4;
#pragma unroll
      for (int nt = 0; nt < 4; ++nt) {
        const int token = n0 + w * 64 + nt * 16 + l15;
        h4 o = {(_Float16)acc[mt][nt][0], (_Float16)acc[mt][nt][1],
                (_Float16)acc[mt][nt][2], (_Float16)acc[mt][nt][3]};
        *(h4*)(buf + (((size_t)b * NH + h) * NN + token) * 64 + dh) = o;
      }
    }
  } else {
    const int h = (d0 - 2 * DD) >> 6;
#pragma unroll
    for (int mt = 0; mt < 4; ++mt) {
      const int dh = mt * 16 + l15;
#pragma unroll
      for (int nt = 0; nt < 4; ++nt) {
        const int token = n0 + w * 64 + nt * 16 + quad * 4;
        h4 o = {(_Float16)acc[mt][nt][0], (_Float16)acc[mt][nt][1],
                (_Float16)acc[mt][nt][2], (_Float16)acc[mt][nt][3]};
        *(h4*)(vb + (((size_t)b * NH + h) * 64 + dh) * NN + token) = o;
      }
    }
  }
}

// ---------------------------------------------------------------------------
// Kernel 2: MFMA flash attention (R4-proven structure). K-split x2, LDS-staged
// K/V, no-max softmax (p = exp2(s*C1 + bias')), bias from frag-ordered table.
// Writes normalized O partials (f16) + l partials (f32).
// ---------------------------------------------------------------------------
__global__ __launch_bounds__(128, 3) void attn_k(
    const _Float16* __restrict__ qb, const _Float16* __restrict__ kb,
    const _Float16* __restrict__ vb, const _Float16* __restrict__ btf,
    _Float16* __restrict__ op, float* __restrict__ lp)
{
  __shared__ _Float16 Ks[64][72];
  __shared__ _Float16 Vs[64][72];
  __shared__ _Float16 Ps[2][32][72];

  const int t    = threadIdx.x;
  const int lane = t & 63;
  const int w    = t >> 6;
  const int l15  = lane & 15;
  const int quad = lane >> 4;
  const int qt = blockIdx.x >> 1;
  const int s  = blockIdx.x & 1;
  const int h = blockIdx.y, b = blockIdx.z;
  const int n0 = qt * 64;
  const size_t base = ((size_t)b * NH + h) * NN * 64;
  const _Float16* qp = qb + base;
  const _Float16* kp = kb + base;
  const _Float16* vp = vb + base;  // [dh][n]

  h8 qf[2][2];
#pragma unroll
  for (int nt = 0; nt < 2; ++nt)
#pragma unroll
    for (int ks = 0; ks < 2; ++ks)
      qf[nt][ks] = *(const h8*)(qp + (size_t)(n0 + w * 32 + nt * 16 + l15) * 64 +
                                ks * 32 + quad * 8);

  f4 oc[4][2];
#pragma unroll
  for (int mt = 0; mt < 4; ++mt)
#pragma unroll
    for (int nt = 0; nt < 2; ++nt) oc[mt][nt] = (f4)(0.f);
  float lacc[2][4] = {};

  const int srow = t >> 3, soff = (t & 7) * 8;
  const _Float16* bp = btf + (((size_t)qt * 36 + s * KTILES) * 128 + t) * 32;

  for (int kt = 0; kt < KTILES; ++kt) {
    const int k0 = (s * KTILES + kt) * 64;
    h8 kr[4], vr[4], br[4];
#pragma unroll
    for (int r = 0; r < 4; ++r) {
      const int row = srow + r * 16;
      kr[r] = *(const h8*)(kp + (size_t)(k0 + row) * 64 + soff);
      vr[r] = *(const h8*)(vp + (size_t)row * NN + k0 + soff);
      br[r] = *(const h8*)(bp + r * 8);
    }
    bp += 128 * 32;
    __syncthreads();  // all waves done reading previous tile's LDS
#pragma unroll
    for (int r = 0; r < 4; ++r) {
      const int row = srow + r * 16;
      *(h8*)&Ks[row][soff] = kr[r];
      *(h8*)&Vs[row][soff] = vr[r];
    }
    __syncthreads();

    // ---- S^T = K * Q^T ----
    f4 st[4][2];
#pragma unroll
    for (int mt = 0; mt < 4; ++mt)
#pragma unroll
      for (int nt = 0; nt < 2; ++nt) st[mt][nt] = (f4)(0.f);
#pragma unroll
    for (int ks = 0; ks < 2; ++ks)
#pragma unroll
      for (int mt = 0; mt < 4; ++mt) {
        h8 kf = *(const h8*)&Ks[mt * 16 + l15][ks * 32 + quad * 8];
#pragma unroll
        for (int nt = 0; nt < 2; ++nt)
          st[mt][nt] = __builtin_amdgcn_mfma_f32_16x16x32_f16(
              kf, qf[nt][ks], st[mt][nt], 0, 0, 0);
      }

    // ---- p = exp2(s*C1 + bias'), no max tracking ----
#pragma unroll
    for (int nt = 0; nt < 2; ++nt) {
      const int q = nt * 16 + l15;
#pragma unroll
      for (int mt = 0; mt < 4; ++mt) {
        h4 pk;
#pragma unroll
        for (int r = 0; r < 4; ++r) {
          const int j = nt * 16 + mt * 4 + r;
          const float bias = (float)br[j >> 3][j & 7];
          const float p = __builtin_exp2f(st[mt][nt][r] * C1 + bias);
          lacc[nt][r] += p;
          pk[r] = (_Float16)p;
        }
        *(h4*)&Ps[w][q][mt * 16 + quad * 4] = pk;  // wave-private
      }
    }

    // ---- O^T += V^T * P^T ----
#pragma unroll
    for (int ks = 0; ks < 2; ++ks) {
      h8 pf[2];
#pragma unroll
      for (int nt = 0; nt < 2; ++nt)
        pf[nt] = *(const h8*)&Ps[w][nt * 16 + l15][ks * 32 + quad * 8];
#pragma unroll
      for (int mt = 0; mt < 4; ++mt) {
        h8 vf = *(const h8*)&Vs[mt * 16 + l15][ks * 32 + quad * 8];
#pragma unroll
        for (int nt = 0; nt < 2; ++nt)
          oc[mt][nt] = __builtin_amdgcn_mfma_f32_16x16x32_f16(
              vf, pf[nt], oc[mt][nt], 0, 0, 0);
      }
    }
  }

  // ---- epilogue: normalized partial O (f16) + l (f32) ----
#pragma unroll
  for (int nt = 0; nt < 2; ++nt) {
    float l = lacc[nt][0] + lacc[nt][1] + lacc[nt][2] + lacc[nt][3];
    l += __shfl_xor(l, 16);
    l += __shfl_xor(l, 32);
    const float inv = 1.f / l;
    const int qi = n0 + w * 32 + nt * 16 + l15;
    _Float16* od = op + (size_t)s * BB * NN * DD +
                   ((size_t)b * NN + qi) * DD + h * 64;
#pragma unroll
    for (int mt = 0; mt < 4; ++mt) {
      const int dh = mt * 16 + quad * 4;
      h4 o = {(_Float16)(oc[mt][nt][0] * inv), (_Float16)(oc[mt][nt][1] * inv),
              (_Float16)(oc[mt][nt][2] * inv), (_Float16)(oc[mt][nt][3] * inv)};
      *(h4*)(od + dh) = o;
    }
    if (quad == 0)
      lp[(size_t)s * BB * NH * NN + ((size_t)b * NH + h) * NN + qi] = l;
  }
}

// ---------------------------------------------------------------------------
// Kernel 3: fused split-combine + out-projection GEMM. 64x64 tile, one wave.
// A tile built in-register: A[n][d] = o0*w0 + o1*w1 (weights from l partials),
// converted f16 into LDS. W staged via double-buffered gload16.
// out[b][o][n] = A x woh^T + bias.
// ---------------------------------------------------------------------------
__global__ __launch_bounds__(64) void outcomb_k(
    const _Float16* __restrict__ op, const float* __restrict__ lp,
    const _Float16* __restrict__ woh, const float* __restrict__ bias,
    float* __restrict__ out)
{
  __shared__ _Float16 Hs[64][32];
  __shared__ _Float16 Ws2[2][64][32];
  const int t = threadIdx.x;
  const int l15 = t & 15, quad = t >> 4;
  const int n0 = blockIdx.x * 64;
  const int o0 = blockIdx.y * 64;
  const int b  = blockIdx.z;
  const int lrow = t >> 2, lcol = (t & 3) * 8;
  const size_t SZO = (size_t)BB * NN * DD;
  const size_t SZL = (size_t)BB * NH * NN;

  f4 acc[4][4];
#pragma unroll
  for (int mt = 0; mt < 4; ++mt)
#pragma unroll
    for (int nt = 0; nt < 4; ++nt) acc[mt][nt] = (f4)(0.f);

  auto stage_w = [&](int bf, int c0) {
#pragma unroll
    for (int k = 0; k < 4; ++k)
      gload16(woh + (size_t)(o0 + k * 16 + lrow) * DD + c0 + lcol,
              &Ws2[bf][k * 16][0]);
  };

  stage_w(0, 0);
  for (int i = 0; i < 16; ++i) {
    const int cur = i & 1;
    const int c0 = i * 32;
    const int h = c0 >> 6;
    // build combined A rows for this chunk (global loads, then LDS after sync)
    h8 a[4];
#pragma unroll
    for (int k = 0; k < 4; ++k) {
      const int row = n0 + k * 16 + lrow;
      const float l0 = lp[((size_t)b * NH + h) * NN + row];
      const float l1 = lp[SZL + ((size_t)b * NH + h) * NN + row];
      const float inv = 1.f / (l0 + l1);
      const float w0 = l0 * inv, w1 = l1 * inv;
      const size_t off = ((size_t)b * NN + row) * DD + c0 + lcol;
      h8 o0v = *(const h8*)(op + off);
      h8 o1v = *(const h8*)(op + SZO + off);
#pragma unroll
      for (int e = 0; e < 8; ++e)
        a[k][e] = (_Float16)((float)o0v[e] * w0 + (float)o1v[e] * w1);
    }
    __syncthreads();  // prior LDS reads done + stage_w(cur) vmcnt drained
#pragma unroll
    for (int k = 0; k < 4; ++k)
      *(h8*)&Hs[k * 16 + lrow][lcol] = a[k];
    if (i < 15) stage_w(cur ^ 1, c0 + 32);
    __syncthreads();  // Hs visible (single wave: cheap)

    h8 hf[4], wf[4];
#pragma unroll
    for (int mt = 0; mt < 4; ++mt)
      hf[mt] = *(const h8*)&Hs[mt * 16 + l15][quad * 8];
#pragma unroll
    for (int nt = 0; nt < 4; ++nt)
      wf[nt] = *(const h8*)&Ws2[cur][nt * 16 + l15][quad * 8];
#pragma unroll
    for (int mt = 0; mt < 4; ++mt)
#pragma unroll
      for (int nt = 0; nt < 4; ++nt)
        acc[mt][nt] = __builtin_amdgcn_mfma_f32_16x16x32_f16(
            hf[mt], wf[nt], acc[mt][nt], 0, 0, 0);
  }

#pragma unroll
  for (int nt = 0; nt < 4; ++nt) {
    const int o = o0 + nt * 16 + l15;
    const float bv = bias[o];
#pragma unroll
    for (int mt = 0; mt < 4; ++mt) {
      const int token = n0 + mt * 16 + quad * 4;
      float4 v = {acc[mt][nt][0] + bv, acc[mt][nt][1] + bv,
                  acc[mt][nt][2] + bv, acc[mt][nt][3] + bv};
      *(float4*)(out + ((size_t)b * DD + o) * NN + token) = v;
    }
  }
}

extern "C" void kernel_launch(void* const* d_in, const int* in_sizes, int n_in,
                              void* d_out, int out_size, void* d_ws, size_t ws_size,
                              hipStream_t stream)
{
  (void)in_sizes; (void)n_in; (void)out_size; (void)ws_size;
  const float* x     = (const float*)d_in[0];
  const float* w_qkv = (const float*)d_in[1];
  const float* w_out = (const float*)d_in[2];
  const float* b_out = (const float*)d_in[3];
  const float* wav   = (const float*)d_in[4];
  float* out = (float*)d_out;

  const size_t SZ  = (size_t)BB * NH * NN * 64;   // 2,359,296 (h16)
  const size_t BTF = (size_t)36 * 36 * 128 * 32;  // 5,308,416 (h16)

  _Float16* qb  = (_Float16*)d_ws;
  _Float16* kb  = qb + SZ;
  _Float16* vb  = kb + SZ;
  _Float16* btf = vb + SZ;
  _Float16* op  = btf + BTF;               // 2*SZ normalized partial O (f16)
  float*    lpf = (float*)(op + 2 * SZ);   // 2*B*NH*NN f32
  _Float16* woh = (_Float16*)(lpf + 2 * (size_t)BB * NH * NN);
  // aliases (lifetime-disjoint):
  _Float16* xt  = op;        // x^T f16, dead after qkv_gemm (op written by attn)
  _Float16* wqh = op + SZ;   // w_qkv f16, dead after qkv_gemm
  // total ws: 3*SZ*2 + BTF*2 + 2*SZ*2 + 0.3MB + 0.5MB = ~35.0 MB

  prep_k    <<<dim3(2304, 3), 256, 0, stream>>>(x, w_qkv, w_out, wav,
                                                btf, xt, wqh, woh);
  qkv_gemm_k<<<dim3(NN / 128, D3 / 64, BB), 128, 0, stream>>>(xt, wqh, qb, kb, vb);
  attn_k    <<<dim3(NN / 64 * NSPLIT, NH, BB), 128, 0, stream>>>(
                 qb, kb, vb, btf, op, lpf);
  outcomb_k <<<dim3(NN / 64, DD / 64, BB), 64, 0, stream>>>(
                 op, lpf, woh, b_out, out);
}